// Round 3
// baseline (210.147 us; speedup 1.0000x reference)
//
#include <hip/hip_runtime.h>

#define C_DIM 256
#define K_NEIGH 32

// ---------------------------------------------------------------------------
// Kernel A: complex linear projection, thread-per-node streaming.
//   tmp[n] = (Whr[n]·Wr - Whi[n]·Wi + br,  Whr[n]·Wi + Whi[n]·Wr + bi)
// Block = 256 threads = 4 waves. Lane l of every wave owns node base+l;
// wave q (=quarter) accumulates channels [q*64, q*64+64). No cross-lane
// shuffles — per-thread accumulation, then a 2 KB LDS 4-way combine.
// Each lane streams its row in float4 steps; each 64B line is consumed by
// 4 consecutive iterations of that lane (L1-resident), so line traffic
// matches the coalesced layout while killing the reduction chain.
// ---------------------------------------------------------------------------
__global__ __launch_bounds__(256) void proj_kernel(
    const float* __restrict__ whr, const float* __restrict__ whi,
    const float* __restrict__ wr,  const float* __restrict__ wi,
    const float* __restrict__ br,  const float* __restrict__ bi,
    float2* __restrict__ tmp, int n_nodes)
{
    const int l = threadIdx.x & 63;   // node within this block's 64-node chunk
    const int q = threadIdx.x >> 6;   // quarter (wave) 0..3
    const int node = blockIdx.x * 64 + l;

    __shared__ float2 part[4][64];

    float vr = 0.f, vi = 0.f;
    if (node < n_nodes) {
        const float4* ar = (const float4*)(whr + (size_t)node * C_DIM + q * 64);
        const float4* bi4 = (const float4*)(whi + (size_t)node * C_DIM + q * 64);
        const float4* u4 = (const float4*)(wr + q * 64);   // wave-uniform -> s_load
        const float4* v4 = (const float4*)(wi + q * 64);

        #pragma unroll
        for (int c = 0; c < 16; ++c) {       // 16 float4 steps = 64 channels
            const float4 a = ar[c];
            const float4 b = bi4[c];
            const float4 u = u4[c];
            const float4 v = v4[c];
            vr += a.x*u.x + a.y*u.y + a.z*u.z + a.w*u.w
                - (b.x*v.x + b.y*v.y + b.z*v.z + b.w*v.w);
            vi += a.x*v.x + a.y*v.y + a.z*v.z + a.w*v.w
                +  b.x*u.x + b.y*u.y + b.z*u.z + b.w*u.w;
        }
    }
    part[q][l] = make_float2(vr, vi);
    __syncthreads();

    if (q == 0 && node < n_nodes) {          // wave 0 finishes 64 nodes
        const float2 p0 = part[0][l];
        const float2 p1 = part[1][l];
        const float2 p2 = part[2][l];
        const float2 p3 = part[3][l];
        tmp[node] = make_float2(p0.x + p1.x + p2.x + p3.x + br[0],
                                p0.y + p1.y + p2.y + p3.y + bi[0]);
    }
}

// ---------------------------------------------------------------------------
// Kernel B: per-column attention + normalization. One thread per column m.
// Index loads / output stores are streaming with zero reuse -> non-temporal,
// so they don't evict the 800 KB tmp gather table from L2.
// ---------------------------------------------------------------------------
__global__ __launch_bounds__(256) void attn_kernel(
    const int* __restrict__ nneg, const float2* __restrict__ tmp,
    float* __restrict__ out, int m_cols)
{
    const int m = blockIdx.x * blockDim.x + threadIdx.x;
    if (m >= m_cols) return;

    const int cidx = __builtin_nontemporal_load(&nneg[m]);
    const float2 c = tmp[cidx];

    float att[K_NEIGH];
    float s = 0.f;
    #pragma unroll
    for (int k = 0; k < K_NEIGH; ++k) {
        const int idx = __builtin_nontemporal_load(&nneg[(size_t)(k + 1) * m_cols + m]);
        const float2 t = tmp[idx];
        const float a = fmaxf(c.x * t.x + c.y * t.y, 0.f);
        att[k] = a;
        s += a;
    }

    const float r = 1.0f / (s + 0.001f);
    #pragma unroll
    for (int k = 0; k < K_NEIGH; ++k) {
        __builtin_nontemporal_store(att[k] * r, &out[(size_t)k * m_cols + m]);
    }
}

// ---------------------------------------------------------------------------
extern "C" void kernel_launch(void* const* d_in, const int* in_sizes, int n_in,
                              void* d_out, int out_size, void* d_ws, size_t ws_size,
                              hipStream_t stream)
{
    const float* whr = (const float*)d_in[0];
    const float* whi = (const float*)d_in[1];
    const int*   nng = (const int*)d_in[2];
    // d_in[3] = k_neighbors scalar (fixed = 32)
    const float* wr  = (const float*)d_in[4];
    const float* wi  = (const float*)d_in[5];
    const float* br  = (const float*)d_in[6];
    const float* bi  = (const float*)d_in[7];

    const int c_dim   = in_sizes[4];                 // 256
    const int n_nodes = in_sizes[0] / c_dim;         // 100000
    const int m_cols  = in_sizes[2] / (K_NEIGH + 1); // 100000

    float2* tmp = (float2*)d_ws;                     // 2*N floats = 800 KB

    // Kernel A: one block per 64 nodes; 4 waves each own a channel-quarter.
    const int blocksA = (n_nodes + 63) / 64;
    proj_kernel<<<blocksA, 256, 0, stream>>>(whr, whi, wr, wi, br, bi, tmp, n_nodes);

    // Kernel B: one thread per column.
    const int blocksB = (m_cols + 255) / 256;
    attn_kernel<<<blocksB, 256, 0, stream>>>(nng, tmp, (float*)d_out, m_cols);
}

// Round 4
// 53.669 us; speedup vs baseline: 3.9156x; 3.9156x over previous
//
#include <hip/hip_runtime.h>

#define C_DIM 256
#define K_NEIGH 32
#define KG 4                     // k-groups per column
#define KPER (K_NEIGH / KG)      // 8 neighbors per thread
#define COLS_PER_BLOCK 64

// ---------------------------------------------------------------------------
// Kernel A: complex linear projection, one 64-lane wave per node (round-1
// structure — best measured). Each lane holds 4 consecutive channels via
// float4 (16 B/lane, fully coalesced); 12-step butterfly reduce; lane 0
// writes interleaved float2.
// ---------------------------------------------------------------------------
__global__ __launch_bounds__(256) void proj_kernel(
    const float* __restrict__ whr, const float* __restrict__ whi,
    const float* __restrict__ wr,  const float* __restrict__ wi,
    const float* __restrict__ br,  const float* __restrict__ bi,
    float2* __restrict__ tmp, int n_nodes)
{
    const int node = (int)((blockIdx.x * (unsigned)blockDim.x + threadIdx.x) >> 6);
    const int lane = threadIdx.x & 63;
    if (node >= n_nodes) return;

    const float4 a = ((const float4*)(whr + (size_t)node * C_DIM))[lane];
    const float4 b = ((const float4*)(whi + (size_t)node * C_DIM))[lane];
    const float4 u = ((const float4*)wr)[lane];
    const float4 v = ((const float4*)wi)[lane];

    float vr = a.x*u.x + a.y*u.y + a.z*u.z + a.w*u.w
             - (b.x*v.x + b.y*v.y + b.z*v.z + b.w*v.w);
    float vi = a.x*v.x + a.y*v.y + a.z*v.z + a.w*v.w
             +  b.x*u.x + b.y*u.y + b.z*u.z + b.w*u.w;

    #pragma unroll
    for (int off = 32; off > 0; off >>= 1) {
        vr += __shfl_xor(vr, off, 64);
        vi += __shfl_xor(vi, off, 64);
    }

    if (lane == 0) {
        tmp[node] = make_float2(vr + br[0], vi + bi[0]);
    }
}

// ---------------------------------------------------------------------------
// Kernel B: attention + normalization, 4 threads per column.
// Block = 256 threads = 64 columns x 4 k-groups; each thread gathers 8
// neighbors (vs 33 serial before) -> 4x waves (24/CU), 4x shallower gather
// chains. Column sum via 1 KB LDS 4-way combine (stride-1 lanes, no bank
// conflicts). Index loads & output stores coalesced + non-temporal so the
// streaming 26 MB doesn't evict the 800 KB tmp gather table from L2.
// ---------------------------------------------------------------------------
__global__ __launch_bounds__(256) void attn_kernel(
    const int* __restrict__ nneg, const float2* __restrict__ tmp,
    float* __restrict__ out, int m_cols)
{
    const int ml = threadIdx.x & 63;          // column within block
    const int kg = threadIdx.x >> 6;          // k-group 0..3
    const int m  = blockIdx.x * COLS_PER_BLOCK + ml;

    __shared__ float part[KG][COLS_PER_BLOCK];

    float att[KPER];
    float s = 0.f;
    float2 c = make_float2(0.f, 0.f);

    if (m < m_cols) {
        const int cidx = __builtin_nontemporal_load(&nneg[m]);
        c = tmp[cidx];                         // redundant across kg; L1/L2-hot

        #pragma unroll
        for (int j = 0; j < KPER; ++j) {
            const int row = 1 + kg * KPER + j;
            const int idx = __builtin_nontemporal_load(&nneg[(size_t)row * m_cols + m]);
            const float2 t = tmp[idx];
            const float a = fmaxf(c.x * t.x + c.y * t.y, 0.f);
            att[j] = a;
            s += a;
        }
    }
    part[kg][ml] = s;
    __syncthreads();

    if (m < m_cols) {
        const float stot = part[0][ml] + part[1][ml] + part[2][ml] + part[3][ml];
        const float r = 1.0f / (stot + 0.001f);
        #pragma unroll
        for (int j = 0; j < KPER; ++j) {
            const int k = kg * KPER + j;
            __builtin_nontemporal_store(att[j] * r, &out[(size_t)k * m_cols + m]);
        }
    }
}

// ---------------------------------------------------------------------------
extern "C" void kernel_launch(void* const* d_in, const int* in_sizes, int n_in,
                              void* d_out, int out_size, void* d_ws, size_t ws_size,
                              hipStream_t stream)
{
    const float* whr = (const float*)d_in[0];
    const float* whi = (const float*)d_in[1];
    const int*   nng = (const int*)d_in[2];
    // d_in[3] = k_neighbors scalar (fixed = 32)
    const float* wr  = (const float*)d_in[4];
    const float* wi  = (const float*)d_in[5];
    const float* br  = (const float*)d_in[6];
    const float* bi  = (const float*)d_in[7];

    const int c_dim   = in_sizes[4];                 // 256
    const int n_nodes = in_sizes[0] / c_dim;         // 100000
    const int m_cols  = in_sizes[2] / (K_NEIGH + 1); // 100000

    float2* tmp = (float2*)d_ws;                     // 2*N floats = 800 KB

    // Kernel A: wave per node, 4 nodes per 256-thread block.
    const int blocksA = (n_nodes + 3) / 4;
    proj_kernel<<<blocksA, 256, 0, stream>>>(whr, whi, wr, wi, br, bi, tmp, n_nodes);

    // Kernel B: 64 columns per block, 4 threads per column.
    const int blocksB = (m_cols + COLS_PER_BLOCK - 1) / COLS_PER_BLOCK;
    attn_kernel<<<blocksB, 256, 0, stream>>>(nng, tmp, (float*)d_out, m_cols);
}